// Round 2
// baseline (3933.890 us; speedup 1.0000x reference)
//
#include <hip/hip_runtime.h>

typedef _Float16 half2_t __attribute__((ext_vector_type(2)));
typedef __bf16   bf16x8  __attribute__((ext_vector_type(8)));
typedef float    f32x4   __attribute__((ext_vector_type(4)));
typedef unsigned short u16x8 __attribute__((ext_vector_type(8)));
typedef unsigned int  uint32;

#define LSTM_N 32
#define LSTM_T 2048
#define LSTM_D 256
#define LSTM_H 256
#define NG 1024
#define CH 256                    // time-chunk length
#define NCH (LSTM_T / CH)         // 8 chunks
#define MCH (LSTM_N * CH)         // 8192 rows per chunk GEMM

// ---- workspace layout (bytes) ---- total ~34.7 MB (chunked to stay small)
#define OFF_XG   ((size_t)0)
#define SZ_XG    ((size_t)MCH * NG * 4)             // 33,554,432 (xg chunk f32)
#define OFF_WIHB (OFF_XG + SZ_XG)
#define SZ_WIHB  ((size_t)NG * LSTM_D * 2)          // 524,288 (w_ih bf16)
#define OFF_BIAS (OFF_WIHB + SZ_WIHB)
#define SZ_BIAS  ((size_t)4096)
#define OFF_WREG (OFF_BIAS + SZ_BIAS)
#define SZ_WREG  ((size_t)192 * 512 * 4)            // w_hh f16 pairs, reg part
#define OFF_WLDS (OFF_WREG + SZ_WREG)
#define SZ_WLDS  ((size_t)64 * 512 * 4)             // w_hh f16 pairs, LDS part
#define OFF_CST  (OFF_WLDS + SZ_WLDS)
#define SZ_CST   ((size_t)LSTM_N * 256 * 4)         // c state f32
#define OFF_HST  (OFF_CST + SZ_CST)
#define SZ_HST   ((size_t)LSTM_N * 128 * 4)         // h state f16-pairs
#define WS_NEED  (OFF_HST + SZ_HST)                 // ~34.7 MB

// scan-kernel LDS layout
#define SMEM_WLDS_BYTES (512 * 272)                 // 139,264 (272B/thread = odd*16B stride)
#define SMEM_ACT_OFF    SMEM_WLDS_BYTES             // 4KB f32[1024]
#define SMEM_HP_OFF     (SMEM_ACT_OFF + 4096)       // 512B u32[128] h f16-pairs
#define SMEM_TOTAL      (SMEM_HP_OFF + 512)         // 143,872

#if defined(__has_builtin)
#if __has_builtin(__builtin_amdgcn_fdot2)
#define HAVE_FDOT2 1
#endif
#endif

__device__ __forceinline__ float fdot2(uint32 w, uint32 h, float acc) {
#ifdef HAVE_FDOT2
  return __builtin_amdgcn_fdot2(__builtin_bit_cast(half2_t, w),
                                __builtin_bit_cast(half2_t, h), acc, false);
#else
  half2_t wv = __builtin_bit_cast(half2_t, w);
  half2_t hv = __builtin_bit_cast(half2_t, h);
  float r = fmaf((float)wv.x, (float)hv.x, acc);
  return fmaf((float)wv.y, (float)hv.y, r);
#endif
}

__device__ __forceinline__ float sigm(float x) { return 1.f / (1.f + __expf(-x)); }
__device__ __forceinline__ float tanh_fast(float x) { return 2.f / (1.f + __expf(-2.f * x)) - 1.f; }

__device__ __forceinline__ unsigned short f2bf(float f) {
  uint32 u = __builtin_bit_cast(uint32, f);
  uint32 r = (u + 0x7FFFu + ((u >> 16) & 1u)) >> 16;
  return (unsigned short)r;
}

// reduce-scatter over 8 kappa-lanes: lane kap ends with full sum of a[kap].
// All register indices compile-time (rule #20).
__device__ __forceinline__ float bfly8(const float a[8], int kap) {
  float k0[4], g0[4];
  const bool b4 = (kap & 4) != 0;
#pragma unroll
  for (int v = 0; v < 4; ++v) {
    k0[v] = b4 ? a[v + 4] : a[v];
    g0[v] = b4 ? a[v] : a[v + 4];
  }
#pragma unroll
  for (int v = 0; v < 4; ++v) k0[v] += __shfl_xor(g0[v], 4, 64);
  float k1[2], g1[2];
  const bool b2 = (kap & 2) != 0;
#pragma unroll
  for (int v = 0; v < 2; ++v) {
    k1[v] = b2 ? k0[v + 2] : k0[v];
    g1[v] = b2 ? k0[v] : k0[v + 2];
  }
#pragma unroll
  for (int v = 0; v < 2; ++v) k1[v] += __shfl_xor(g1[v], 2, 64);
  const bool b1 = (kap & 1) != 0;
  float k2 = b1 ? k1[1] : k1[0];
  float g2 = b1 ? k1[0] : k1[1];
  return k2 + __shfl_xor(g2, 1, 64);
}

// ---------------- kernels ----------------

__global__ void cvt_bf16_k(const float* __restrict__ src, unsigned short* __restrict__ dst, int n) {
  int i = blockIdx.x * blockDim.x + threadIdx.x;
  if (4 * i + 3 < n) {
    float4 v = ((const float4*)src)[i];
    ushort4 o;
    o.x = f2bf(v.x); o.y = f2bf(v.y); o.z = f2bf(v.z); o.w = f2bf(v.w);
    ((ushort4*)dst)[i] = o;
  }
}

__global__ void bias_sum_k(const float* __restrict__ bih, const float* __restrict__ bhh,
                           float* __restrict__ bias) {
  int g = blockIdx.x * blockDim.x + threadIdx.x;
  if (g < NG) bias[g] = bih[g] + bhh[g];
}

// Pack w_hh (f32 [1024][256]) into f16-pair layouts for the scan kernel.
// Scan thread t: kap=t&7 owns k in [32kap,32kap+32); rg=t>>3 owns rows 16rg..16rg+15.
__global__ void wpack_k(const float* __restrict__ whh, uint32* __restrict__ wreg,
                        uint32* __restrict__ wlds) {
  int e = blockIdx.x * blockDim.x + threadIdx.x;  // < 131072
  int i = e >> 9;
  int t = e & 511;
  int rg = t >> 3, kp = t & 7;
  int rho, p;
  if (i < 192) { rho = i >> 4;               p = i & 15; }
  else         { rho = 12 + ((i - 192) >> 4); p = (i - 192) & 15; }
  int r = 16 * rg + rho;
  int k = 32 * kp + 2 * p;
  half2_t h;
  h.x = (_Float16)whh[r * 256 + k];
  h.y = (_Float16)whh[r * 256 + k + 1];
  uint32 val = __builtin_bit_cast(uint32, h);
  if (i < 192) wreg[((i >> 2) * 512 + t) * 4 + (i & 3)] = val;
  else {
    int q = i - 192;
    wlds[((q >> 2) * 512 + t) * 4 + (q & 3)] = val;
  }
}

// init carried state from input `state`: c f32, h as f16-pairs
__global__ void state_init_k(const float* __restrict__ state, float* __restrict__ cst,
                             uint32* __restrict__ hst) {
  int i = blockIdx.x * blockDim.x + threadIdx.x;  // < 32*256
  int n = i >> 8, j = i & 255;
  cst[i] = state[n * 512 + 256 + j];
  if ((j & 1) == 0) {
    half2_t h2;
    h2.x = (_Float16)state[n * 512 + j];
    h2.y = (_Float16)state[n * 512 + j + 1];
    hst[(n << 7) + (j >> 1)] = __builtin_bit_cast(uint32, h2);
  }
}

// xg_chunk[8192][1024] = x(chunk rows, cvt bf16 inline) @ w_ih_bf16^T + bias
__global__ __launch_bounds__(256) void gemm_xg(const float* __restrict__ x,
                                               const unsigned short* __restrict__ wb,
                                               const float* __restrict__ bias,
                                               float* __restrict__ xg, int ch) {
  __shared__ unsigned short As[128 * 40];  // 80B rows (stride = 5*16B, odd*16)
  __shared__ unsigned short Bs[128 * 40];
  const int tid = threadIdx.x;
  const int m0 = blockIdx.y * 128;
  const int g0 = blockIdx.x * 128;
  const int w = tid >> 6;
  const int lane = tid & 63;
  const int wm = (w >> 1) * 64, wn = (w & 1) * 64;
  const int row_l = tid >> 2;  // 0..63
  const int q = tid & 3;
  const int lr = lane & 15, kg = lane >> 4;

  // global x rows for this thread's two staged tile-rows
  size_t grow[2];
#pragma unroll
  for (int r = 0; r < 2; ++r) {
    int gm = m0 + row_l + 64 * r;                    // chunk-row (n*CH + tl)
    grow[r] = (size_t)(gm >> 8) * LSTM_T + (size_t)ch * CH + (gm & 255);
  }

  f32x4 acc[4][4];
#pragma unroll
  for (int i = 0; i < 4; ++i)
#pragma unroll
    for (int j = 0; j < 4; ++j) acc[i][j] = (f32x4){0.f, 0.f, 0.f, 0.f};

  for (int kt = 0; kt < 8; ++kt) {
#pragma unroll
    for (int r = 0; r < 2; ++r) {
      int row = row_l + 64 * r;
      const float* ap = x + grow[r] * 256 + kt * 32 + q * 8;
      float4 v0 = *(const float4*)ap;
      float4 v1 = *(const float4*)(ap + 4);
      u16x8 o;
      o[0] = f2bf(v0.x); o[1] = f2bf(v0.y); o[2] = f2bf(v0.z); o[3] = f2bf(v0.w);
      o[4] = f2bf(v1.x); o[5] = f2bf(v1.y); o[6] = f2bf(v1.z); o[7] = f2bf(v1.w);
      *(uint4*)((char*)As + row * 80 + q * 16) = __builtin_bit_cast(uint4, o);
      uint4 bv = *(const uint4*)(wb + (size_t)(g0 + row) * 256 + kt * 32 + q * 8);
      *(uint4*)((char*)Bs + row * 80 + q * 16) = bv;
    }
    __syncthreads();
    bf16x8 af[4], bfr[4];
#pragma unroll
    for (int i = 0; i < 4; ++i)
      af[i] = __builtin_bit_cast(bf16x8, *(const uint4*)((char*)As + (wm + 16 * i + lr) * 80 + kg * 16));
#pragma unroll
    for (int j = 0; j < 4; ++j)
      bfr[j] = __builtin_bit_cast(bf16x8, *(const uint4*)((char*)Bs + (wn + 16 * j + lr) * 80 + kg * 16));
#pragma unroll
    for (int i = 0; i < 4; ++i)
#pragma unroll
      for (int j = 0; j < 4; ++j)
        acc[i][j] = __builtin_amdgcn_mfma_f32_16x16x32_bf16(af[i], bfr[j], acc[i][j], 0, 0, 0);
    __syncthreads();
  }
  // C/D layout: col = lane&15 (g), row = (lane>>4)*4 + reg (m)  [guide-verified]
#pragma unroll
  for (int j = 0; j < 4; ++j) {
    int gc = g0 + wn + 16 * j + lr;
    float bj = bias[gc];
#pragma unroll
    for (int i = 0; i < 4; ++i) {
#pragma unroll
      for (int r = 0; r < 4; ++r) {
        int m = m0 + wm + 16 * i + kg * 4 + r;
        xg[(size_t)m * NG + gc] = acc[i][j][r] + bj;
      }
    }
  }
}

// Persistent recurrent scan over one CH-step chunk. 1 WG/sample, 512 threads.
// Thread t: kap=t&7 owns k-slice [32kap,32kap+32); rg=t>>3 owns rows 16rg..16rg+15.
// Rows 0..11 in 192 VGPRs, rows 12..15 streamed from LDS (272B/thread stride).
__global__ __launch_bounds__(512, 2) void lstm_scan(const float* __restrict__ xg,
                                                    const uint32* __restrict__ wreg_g,
                                                    const uint32* __restrict__ wlds_g,
                                                    float* __restrict__ cst,
                                                    uint32* __restrict__ hst,
                                                    float* __restrict__ out, int ch) {
  extern __shared__ char smem[];
  float* actb = (float*)(smem + SMEM_ACT_OFF);
  char* hpb = smem + SMEM_HP_OFF;

  const int tid = threadIdx.x;
  const int n = blockIdx.x;
  const int kap = tid & 7;
  const int rg = tid >> 3;
  const int gtype = tid >> 7;  // wave-uniform: 0=i 1=f 2=g(tanh) 3=o

  // W -> registers (rows 0..11 of each 16-row group)
  uint32 wr[192];
  const uint4* wreg4 = (const uint4*)wreg_g;
#pragma unroll
  for (int ig = 0; ig < 48; ++ig) {
    uint4 v = wreg4[ig * 512 + tid];
    wr[4 * ig + 0] = v.x; wr[4 * ig + 1] = v.y; wr[4 * ig + 2] = v.z; wr[4 * ig + 3] = v.w;
  }
  // W -> LDS (rows 12..15)
  const uint4* wlds4 = (const uint4*)wlds_g;
#pragma unroll
  for (int j = 0; j < 16; ++j) {
    uint4 v = wlds4[j * 512 + tid];
    *(uint4*)(smem + (size_t)tid * 272 + j * 16) = v;
  }
  // carried state
  float c = 0.f;
  if (tid < 256) c = cst[n * 256 + tid];
  if (tid < 128) *(uint32*)(hpb + 4 * tid) = hst[n * 128 + tid];
  __syncthreads();

  const int r0 = 16 * rg + kap;  // row finalized in pass 0 (rho=kap)
  const int r1 = r0 + 8;         // pass 1 (rho=8+kap)
  const float* xgn = xg + (size_t)n * CH * NG;
  float* outb = out + (size_t)n * LSTM_T * LSTM_H + (size_t)ch * CH * LSTM_H;
  float xpre0 = xgn[r0];
  float xpre1 = xgn[r1];

  for (int tt = 0; tt < CH; ++tt) {
    float xg0 = xpre0, xg1 = xpre1;
    if (tt < CH - 1) {  // prefetch next step's xg
      xpre0 = xgn[(size_t)(tt + 1) * NG + r0];
      xpre1 = xgn[(size_t)(tt + 1) * NG + r1];
    }
    // h fragment for this k-slice (8 distinct 16B slots -> broadcast-friendly)
    uint32 hr[16];
#pragma unroll
    for (int j = 0; j < 4; ++j) {
      uint4 v = *(const uint4*)(hpb + 64 * kap + 16 * j);
      hr[4 * j + 0] = v.x; hr[4 * j + 1] = v.y; hr[4 * j + 2] = v.z; hr[4 * j + 3] = v.w;
    }
    float acc[8];
#pragma unroll
    for (int rr = 0; rr < 8; ++rr) {   // pass 0: rows rho 0..7 (registers)
      float a = 0.f;
#pragma unroll
      for (int p = 0; p < 16; ++p) a = fdot2(wr[rr * 16 + p], hr[p], a);
      acc[rr] = a;
    }
    float s0 = bfly8(acc, kap);
#pragma unroll
    for (int rr = 0; rr < 4; ++rr) {   // pass 1a: rows 8..11 (registers)
      float a = 0.f;
#pragma unroll
      for (int p = 0; p < 16; ++p) a = fdot2(wr[(8 + rr) * 16 + p], hr[p], a);
      acc[rr] = a;
    }
#pragma unroll
    for (int rr = 0; rr < 4; ++rr) {   // pass 1b: rows 12..15 (LDS stream)
      float a = 0.f;
#pragma unroll
      for (int jj = 0; jj < 4; ++jj) {
        uint4 wv = *(const uint4*)(smem + (size_t)tid * 272 + rr * 64 + jj * 16);
        a = fdot2(wv.x, hr[4 * jj + 0], a);
        a = fdot2(wv.y, hr[4 * jj + 1], a);
        a = fdot2(wv.z, hr[4 * jj + 2], a);
        a = fdot2(wv.w, hr[4 * jj + 3], a);
      }
      acc[4 + rr] = a;
    }
    float s1 = bfly8(acc, kap);

    float pre0 = s0 + xg0;
    float pre1 = s1 + xg1;
    float a0, a1;
    if (gtype == 2) { a0 = tanh_fast(pre0); a1 = tanh_fast(pre1); }
    else            { a0 = sigm(pre0);      a1 = sigm(pre1); }
    actb[r0] = a0;
    actb[r1] = a1;
    __syncthreads();
    if (tid < 256) {
      float gi = actb[tid];
      float gf = actb[256 + tid];
      float gg = actb[512 + tid];
      float go = actb[768 + tid];
      c = gf * c + gi * gg;
      float h = go * tanh_fast(c);
      _Float16 hf = (_Float16)h;
      *(unsigned short*)(hpb + 2 * tid) = __builtin_bit_cast(unsigned short, hf);
      outb[tt * LSTM_H + tid] = h;
      if (ch == NCH - 1 && tt == CH - 1) {
        float* os = out + (size_t)LSTM_N * LSTM_T * LSTM_H + n * 512;
        os[tid] = h;
        os[256 + tid] = c;
      }
    }
    __syncthreads();
  }
  // persist carried state for next chunk
  if (tid < 256) cst[n * 256 + tid] = c;
  if (tid < 128) hst[n * 128 + tid] = *(uint32*)(hpb + 4 * tid);
}

extern "C" void kernel_launch(void* const* d_in, const int* in_sizes, int n_in,
                              void* d_out, int out_size, void* d_ws, size_t ws_size,
                              hipStream_t stream) {
  const float* x   = (const float*)d_in[0];
  const float* st  = (const float*)d_in[1];
  const float* wih = (const float*)d_in[2];
  const float* whh = (const float*)d_in[3];
  const float* bih = (const float*)d_in[4];
  const float* bhh = (const float*)d_in[5];
  float* out = (float*)d_out;
  char* ws = (char*)d_ws;

  float* xg = (float*)(ws + OFF_XG);
  unsigned short* wihb = (unsigned short*)(ws + OFF_WIHB);
  float* bias = (float*)(ws + OFF_BIAS);
  uint32* wreg = (uint32*)(ws + OFF_WREG);
  uint32* wlds = (uint32*)(ws + OFF_WLDS);
  float* cst = (float*)(ws + OFF_CST);
  uint32* hst = (uint32*)(ws + OFF_HST);

  // allow >64KB dynamic LDS for the scan kernel (no-op if already allowed)
  (void)hipFuncSetAttribute(reinterpret_cast<const void*>(lstm_scan),
                            hipFuncAttributeMaxDynamicSharedMemorySize, SMEM_TOTAL);

  cvt_bf16_k<<<(NG * LSTM_D / 4 + 255) / 256, 256, 0, stream>>>(wih, wihb, NG * LSTM_D);
  bias_sum_k<<<4, 256, 0, stream>>>(bih, bhh, bias);
  wpack_k<<<512, 256, 0, stream>>>(whh, wreg, wlds);
  state_init_k<<<32, 256, 0, stream>>>(st, cst, hst);

  for (int ch = 0; ch < NCH; ++ch) {
    gemm_xg<<<dim3(NG / 128, MCH / 128), 256, 0, stream>>>(x, wihb, bias, xg, ch);
    lstm_scan<<<LSTM_N, 512, SMEM_TOTAL, stream>>>(xg, wreg, wlds, cst, hst, out, ch);
  }
}

// Round 3
// 3450.015 us; speedup vs baseline: 1.1403x; 1.1403x over previous
//
#include <hip/hip_runtime.h>

typedef _Float16 half2_t __attribute__((ext_vector_type(2)));
typedef __bf16   bf16x8  __attribute__((ext_vector_type(8)));
typedef float    f32x4   __attribute__((ext_vector_type(4)));
typedef unsigned short u16x8 __attribute__((ext_vector_type(8)));
typedef unsigned int  uint32;
typedef unsigned long long uint64;

#define LSTM_N 32
#define LSTM_T 2048
#define LSTM_D 256
#define LSTM_H 256
#define NG 1024
#define CH 256                    // time-chunk length
#define NCH (LSTM_T / CH)         // 8 chunks
#define MCH (LSTM_N * CH)         // 8192 rows per chunk GEMM

// ---- workspace layout (bytes) ----
#define OFF_XG   ((size_t)0)
#define SZ_XG    ((size_t)MCH * NG * 4)             // 33,554,432 (xg chunk f32)
#define OFF_WIHB (OFF_XG + SZ_XG)
#define SZ_WIHB  ((size_t)NG * LSTM_D * 2)          // w_ih bf16
#define OFF_BIAS (OFF_WIHB + SZ_WIHB)
#define SZ_BIAS  ((size_t)4096)
#define OFF_WPK  (OFF_BIAS + SZ_BIAS)
#define SZ_WPK   ((size_t)2 * 32 * 512 * 16)        // 524,288 w_hh f16 pairs (per-WG reg layout)
#define OFF_CST  (OFF_WPK + SZ_WPK)
#define SZ_CST   ((size_t)LSTM_N * 256 * 4)         // c state f32
#define OFF_HST  (OFF_CST + SZ_CST)
#define SZ_HST   ((size_t)LSTM_N * 128 * 4)         // h state f16-pairs
#define OFF_HX   (OFF_HST + SZ_HST)
#define SZ_HX    ((size_t)LSTM_N * 2 * 2 * 64 * 8)  // 65,536 exchange slots (tagged u64)

#if defined(__has_builtin)
#if __has_builtin(__builtin_amdgcn_fdot2)
#define HAVE_FDOT2 1
#endif
#endif

__device__ __forceinline__ float fdot2(uint32 w, uint32 h, float acc) {
#ifdef HAVE_FDOT2
  return __builtin_amdgcn_fdot2(__builtin_bit_cast(half2_t, w),
                                __builtin_bit_cast(half2_t, h), acc, false);
#else
  half2_t wv = __builtin_bit_cast(half2_t, w);
  half2_t hv = __builtin_bit_cast(half2_t, h);
  float r = fmaf((float)wv.x, (float)hv.x, acc);
  return fmaf((float)wv.y, (float)hv.y, r);
#endif
}

__device__ __forceinline__ float sigm(float x) { return 1.f / (1.f + __expf(-x)); }
__device__ __forceinline__ float tanh_fast(float x) { return 2.f / (1.f + __expf(-2.f * x)) - 1.f; }

__device__ __forceinline__ unsigned short f2bf(float f) {
  uint32 u = __builtin_bit_cast(uint32, f);
  uint32 r = (u + 0x7FFFu + ((u >> 16) & 1u)) >> 16;
  return (unsigned short)r;
}

// reduce-scatter over 8 kappa-lanes: lane kap ends with full sum of a[kap].
// All register indices compile-time (rule #20). Verified in Round 2.
__device__ __forceinline__ float bfly8(const float a[8], int kap) {
  float k0[4], g0[4];
  const bool b4 = (kap & 4) != 0;
#pragma unroll
  for (int v = 0; v < 4; ++v) {
    k0[v] = b4 ? a[v + 4] : a[v];
    g0[v] = b4 ? a[v] : a[v + 4];
  }
#pragma unroll
  for (int v = 0; v < 4; ++v) k0[v] += __shfl_xor(g0[v], 4, 64);
  float k1[2], g1[2];
  const bool b2 = (kap & 2) != 0;
#pragma unroll
  for (int v = 0; v < 2; ++v) {
    k1[v] = b2 ? k0[v + 2] : k0[v];
    g1[v] = b2 ? k0[v] : k0[v + 2];
  }
#pragma unroll
  for (int v = 0; v < 2; ++v) k1[v] += __shfl_xor(g1[v], 2, 64);
  const bool b1 = (kap & 1) != 0;
  float k2 = b1 ? k1[1] : k1[0];
  float g2 = b1 ? k1[0] : k1[1];
  return k2 + __shfl_xor(g2, 1, 64);
}

// ---------------- kernels ----------------

__global__ void cvt_bf16_k(const float* __restrict__ src, unsigned short* __restrict__ dst, int n) {
  int i = blockIdx.x * blockDim.x + threadIdx.x;
  if (4 * i + 3 < n) {
    float4 v = ((const float4*)src)[i];
    ushort4 o;
    o.x = f2bf(v.x); o.y = f2bf(v.y); o.z = f2bf(v.z); o.w = f2bf(v.w);
    ((ushort4*)dst)[i] = o;
  }
}

__global__ void bias_sum_k(const float* __restrict__ bih, const float* __restrict__ bhh,
                           float* __restrict__ bias) {
  int g = blockIdx.x * blockDim.x + threadIdx.x;
  if (g < NG) bias[g] = bih[g] + bhh[g];
}

// Pack w_hh f32[1024][256] -> per-(WG p, thread t) f16-pair reg images.
// Scan WG p owns gate rows {q*256 + 128p + u}; thread t: kap=t&7, rg=t>>3,
// local rows lr=8rg+rho (rho 0..7, q=lr>>7, u=lr&127); k-slice: j<8 own half
// (k=128p+16kap+2j), j>=8 peer half (k=128(1-p)+16kap+2(j-8)).
__global__ void wpack_k(const float* __restrict__ whh, uint32* __restrict__ wpk) {
  int e = blockIdx.x * blockDim.x + threadIdx.x;  // < 131072
  int p = e >> 16;
  int rem = e & 0xFFFF;
  int i = rem >> 9;        // 0..127
  int t = rem & 511;
  int rho = i >> 4, j = i & 15;
  int kap = t & 7, rg = t >> 3;
  int lr = 8 * rg + rho;
  int q = lr >> 7, u = lr & 127;
  int r = q * 256 + 128 * p + u;
  int k = (j < 8) ? (128 * p + 16 * kap + 2 * j)
                  : (128 * (1 - p) + 16 * kap + 2 * (j - 8));
  half2_t h;
  h.x = (_Float16)whh[r * 256 + k];
  h.y = (_Float16)whh[r * 256 + k + 1];
  wpk[((p * 32 + (i >> 2)) * 512 + t) * 4 + (i & 3)] = __builtin_bit_cast(uint32, h);
}

// init carried state + zero exchange tags (every launch -> replay-safe)
__global__ void state_init_k(const float* __restrict__ state, float* __restrict__ cst,
                             uint32* __restrict__ hst, uint64* __restrict__ hx) {
  int i = blockIdx.x * blockDim.x + threadIdx.x;  // < 8192
  int n = i >> 8, j = i & 255;
  cst[i] = state[n * 512 + 256 + j];
  if ((j & 1) == 0) {
    half2_t h2;
    h2.x = (_Float16)state[n * 512 + j];
    h2.y = (_Float16)state[n * 512 + j + 1];
    hst[(n << 7) + (j >> 1)] = __builtin_bit_cast(uint32, h2);
  }
  hx[i] = 0ull;
}

// xg_chunk[8192][1024] = x(chunk rows, cvt bf16 inline) @ w_ih_bf16^T + bias
__global__ __launch_bounds__(256) void gemm_xg(const float* __restrict__ x,
                                               const unsigned short* __restrict__ wb,
                                               const float* __restrict__ bias,
                                               float* __restrict__ xg, int ch) {
  __shared__ unsigned short As[128 * 40];  // 80B rows (stride = 5*16B, odd*16)
  __shared__ unsigned short Bs[128 * 40];
  const int tid = threadIdx.x;
  const int m0 = blockIdx.y * 128;
  const int g0 = blockIdx.x * 128;
  const int w = tid >> 6;
  const int lane = tid & 63;
  const int wm = (w >> 1) * 64, wn = (w & 1) * 64;
  const int row_l = tid >> 2;  // 0..63
  const int q = tid & 3;
  const int lr = lane & 15, kg = lane >> 4;

  size_t grow[2];
#pragma unroll
  for (int r = 0; r < 2; ++r) {
    int gm = m0 + row_l + 64 * r;
    grow[r] = (size_t)(gm >> 8) * LSTM_T + (size_t)ch * CH + (gm & 255);
  }

  f32x4 acc[4][4];
#pragma unroll
  for (int i = 0; i < 4; ++i)
#pragma unroll
    for (int j = 0; j < 4; ++j) acc[i][j] = (f32x4){0.f, 0.f, 0.f, 0.f};

  for (int kt = 0; kt < 8; ++kt) {
#pragma unroll
    for (int r = 0; r < 2; ++r) {
      int row = row_l + 64 * r;
      const float* ap = x + grow[r] * 256 + kt * 32 + q * 8;
      float4 v0 = *(const float4*)ap;
      float4 v1 = *(const float4*)(ap + 4);
      u16x8 o;
      o[0] = f2bf(v0.x); o[1] = f2bf(v0.y); o[2] = f2bf(v0.z); o[3] = f2bf(v0.w);
      o[4] = f2bf(v1.x); o[5] = f2bf(v1.y); o[6] = f2bf(v1.z); o[7] = f2bf(v1.w);
      *(uint4*)((char*)As + row * 80 + q * 16) = __builtin_bit_cast(uint4, o);
      uint4 bv = *(const uint4*)(wb + (size_t)(g0 + row) * 256 + kt * 32 + q * 8);
      *(uint4*)((char*)Bs + row * 80 + q * 16) = bv;
    }
    __syncthreads();
    bf16x8 af[4], bfr[4];
#pragma unroll
    for (int i = 0; i < 4; ++i)
      af[i] = __builtin_bit_cast(bf16x8, *(const uint4*)((char*)As + (wm + 16 * i + lr) * 80 + kg * 16));
#pragma unroll
    for (int j = 0; j < 4; ++j)
      bfr[j] = __builtin_bit_cast(bf16x8, *(const uint4*)((char*)Bs + (wn + 16 * j + lr) * 80 + kg * 16));
#pragma unroll
    for (int i = 0; i < 4; ++i)
#pragma unroll
      for (int j = 0; j < 4; ++j)
        acc[i][j] = __builtin_amdgcn_mfma_f32_16x16x32_bf16(af[i], bfr[j], acc[i][j], 0, 0, 0);
    __syncthreads();
  }
#pragma unroll
  for (int j = 0; j < 4; ++j) {
    int gc = g0 + wn + 16 * j + lr;
    float bj = bias[gc];
#pragma unroll
    for (int i = 0; i < 4; ++i) {
#pragma unroll
      for (int r = 0; r < 4; ++r) {
        int m = m0 + wm + 16 * i + kg * 4 + r;
        xg[(size_t)m * NG + gc] = acc[i][j][r] + bj;
      }
    }
  }
}

// Recurrent scan, 2 WGs per sample (b = n + 32*p -> pair lands on same XCD
// under round-robin; correctness doesn't depend on it). WG p owns hidden
// units [128p,128p+128) x 4 gates = 512 rows; all weights in 128 arch VGPRs.
// Per-step h-half exchange via tagged 8B agent-scope atomics, parity dbuf.
__global__ __launch_bounds__(512, 2) void lstm_scan(const float* __restrict__ xg,
                                                    const uint4* __restrict__ wpk4,
                                                    float* __restrict__ cst,
                                                    uint32* __restrict__ hst,
                                                    uint64* __restrict__ hx,
                                                    float* __restrict__ out, int ch) {
  __shared__ float actb[512];
  __shared__ uint32 hbuf[128];   // full h as f16 pairs (k = 2*idx, 2*idx+1)

  const int tid = threadIdx.x;
  const int b = blockIdx.x;
  const int n = b & 31;
  const int p = b >> 5;
  const int kap = tid & 7;
  const int rg = tid >> 3;
  const int lrf = 8 * rg + kap;          // local row this lane finalizes
  const int q = lrf >> 7, u = lrf & 127;
  const int grow = q * 256 + 128 * p + u;  // global gate row

  // weights -> 128 arch VGPRs (32 x uint4)
  uint32 wr[128];
#pragma unroll
  for (int ig = 0; ig < 32; ++ig) {
    uint4 v = wpk4[(p * 32 + ig) * 512 + tid];
    wr[4 * ig + 0] = v.x; wr[4 * ig + 1] = v.y; wr[4 * ig + 2] = v.z; wr[4 * ig + 3] = v.w;
  }
  // carried state
  float c = 0.f;
  if (tid < 128) {
    c = cst[n * 256 + 128 * p + tid];
    hbuf[tid] = hst[n * 128 + tid];      // full h (both halves) from global
  }
  __syncthreads();

  const float* xgn = xg + (size_t)n * CH * NG;
  float* outb = out + ((size_t)n * LSTM_T + (size_t)ch * CH) * LSTM_H;
  uint64* hx_own  = hx + (size_t)((n * 2 + p) * 2) * 64;
  uint64* hx_peer = hx + (size_t)((n * 2 + (1 - p)) * 2) * 64;
  const int gsbase = ch * CH;
  const int ownbase  = 64 * p + 8 * kap;
  const int peerbase = 64 * (1 - p) + 8 * kap;

  float xpre = xgn[grow];

  for (int tt = 0; tt < CH; ++tt) {
    // wave 0: fetch peer h-half (tag==gs carried inside the 8B atomic)
    if (tt > 0 && tid < 64) {
      const uint32 gs = (uint32)(gsbase + tt);
      uint64 v;
      do {
        v = __hip_atomic_load(&hx_peer[(gs & 1) * 64 + tid], __ATOMIC_RELAXED,
                              __HIP_MEMORY_SCOPE_AGENT);
      } while ((uint32)(v >> 32) != gs);
      hbuf[64 * (1 - p) + tid] = (uint32)v;
    }
    // A: own-half partial (overlaps wave0's poll)
    uint32 hro[8];
    *(uint4*)&hro[0] = *(const uint4*)&hbuf[ownbase];
    *(uint4*)&hro[4] = *(const uint4*)&hbuf[ownbase + 4];
    float acc[8];
#pragma unroll
    for (int rho = 0; rho < 8; ++rho) {
      float a = 0.f;
#pragma unroll
      for (int j = 0; j < 8; ++j) a = fdot2(wr[rho * 16 + j], hro[j], a);
      acc[rho] = a;
    }
    __syncthreads();   // peer half now in LDS
    // C: peer-half partial + reduce + activation
    uint32 hrp[8];
    *(uint4*)&hrp[0] = *(const uint4*)&hbuf[peerbase];
    *(uint4*)&hrp[4] = *(const uint4*)&hbuf[peerbase + 4];
#pragma unroll
    for (int rho = 0; rho < 8; ++rho) {
      float a = acc[rho];
#pragma unroll
      for (int j = 0; j < 8; ++j) a = fdot2(wr[rho * 16 + 8 + j], hrp[j], a);
      acc[rho] = a;
    }
    float s = bfly8(acc, kap);
    float pre = s + xpre;
    if (tt < CH - 1) xpre = xgn[(size_t)(tt + 1) * NG + grow];  // prefetch
    float a0 = (q == 2) ? tanh_fast(pre) : sigm(pre);
    actb[lrf] = a0;
    __syncthreads();
    // E: cell update (units u = tid, local)
    if (tid < 128) {
      float gi = actb[tid];
      float gf = actb[128 + tid];
      float gg = actb[256 + tid];
      float go = actb[384 + tid];
      c = gf * c + gi * gg;
      float h = go * tanh_fast(c);
      _Float16 hf = (_Float16)h;
      ((unsigned short*)hbuf)[128 * p + tid] = __builtin_bit_cast(unsigned short, hf);
      outb[(size_t)tt * LSTM_H + 128 * p + tid] = h;
      if (ch == NCH - 1 && tt == CH - 1) {
        float* os = out + (size_t)LSTM_N * LSTM_T * LSTM_H + n * 512;
        os[128 * p + tid] = h;
        os[256 + 128 * p + tid] = c;
      }
    }
    __syncthreads();   // own h-half updated in LDS
    // G: post own half for peer's next step
    if (tt < CH - 1 && tid < 64) {
      const uint32 gs = (uint32)(gsbase + tt + 1);
      uint64 v = (uint64)hbuf[64 * p + tid] | ((uint64)gs << 32);
      __hip_atomic_store(&hx_own[(gs & 1) * 64 + tid], v, __ATOMIC_RELAXED,
                         __HIP_MEMORY_SCOPE_AGENT);
    }
  }
  // persist carried state for next chunk (full h via both WGs' halves)
  if (tid < 128) cst[n * 256 + 128 * p + tid] = c;
  if (tid < 64) hst[n * 128 + 64 * p + tid] = hbuf[64 * p + tid];
}

extern "C" void kernel_launch(void* const* d_in, const int* in_sizes, int n_in,
                              void* d_out, int out_size, void* d_ws, size_t ws_size,
                              hipStream_t stream) {
  const float* x   = (const float*)d_in[0];
  const float* st  = (const float*)d_in[1];
  const float* wih = (const float*)d_in[2];
  const float* whh = (const float*)d_in[3];
  const float* bih = (const float*)d_in[4];
  const float* bhh = (const float*)d_in[5];
  float* out = (float*)d_out;
  char* ws = (char*)d_ws;

  float* xg = (float*)(ws + OFF_XG);
  unsigned short* wihb = (unsigned short*)(ws + OFF_WIHB);
  float* bias = (float*)(ws + OFF_BIAS);
  uint32* wpk = (uint32*)(ws + OFF_WPK);
  float* cst = (float*)(ws + OFF_CST);
  uint32* hst = (uint32*)(ws + OFF_HST);
  uint64* hx = (uint64*)(ws + OFF_HX);

  cvt_bf16_k<<<(NG * LSTM_D / 4 + 255) / 256, 256, 0, stream>>>(wih, wihb, NG * LSTM_D);
  bias_sum_k<<<4, 256, 0, stream>>>(bih, bhh, bias);
  wpack_k<<<512, 256, 0, stream>>>(whh, wpk);
  state_init_k<<<32, 256, 0, stream>>>(st, cst, hst, hx);

  for (int ch = 0; ch < NCH; ++ch) {
    gemm_xg<<<dim3(NG / 128, MCH / 128), 256, 0, stream>>>(x, wihb, bias, xg, ch);
    lstm_scan<<<64, 512, 0, stream>>>(xg, (const uint4*)wpk, cst, hst, hx, out, ch);
  }
}